// Round 18
// baseline (4279.650 us; speedup 1.0000x reference)
//
#include <hip/hip_runtime.h>
#include <hip/hip_bf16.h>

#define B 16
#define P 1024
#define NPT 16384   // B*P
#define KNN 16
#define MID 96
#define HD 64

// ws layout (in floats)
#define WS_UV   0                        // NPT*192  (aliased as pkeys: NPT*2*16 u64 = 4.2MB < 12.58MB)
#define WS_RN   (WS_UV + NPT*192)        // NPT
#define WS_NBR  (WS_RN + NPT)            // NPT*KNN ints
#define WS_WUV  (WS_NBR + NPT*KNN)       // up to 192*192
#define WS_CVEC (WS_WUV + 192*192)       // 96
#define WS_PART (WS_CVEC + 96)           // B*16*256
#define WS_XT   (WS_PART + 16*16*256)    // B*192*1024 floats (transposed features)

#define NCH 2        // chunk lists per row (512 cands per chunk)

typedef float f32x2 __attribute__((ext_vector_type(2)));

// VOP3P packed fma with op_sel broadcast of one src1 half (no splat movs).
// lo = fma(c.lo, r.lo, acc.lo); hi = fma(c.hi, r.lo, acc.hi)
__device__ __forceinline__ void pk_lo(f32x2 &acc, f32x2 c, f32x2 r) {
    asm("v_pk_fma_f32 %0, %1, %2, %0 op_sel:[0,0,0] op_sel_hi:[1,0,1]"
        : "+v"(acc) : "v"(c), "v"(r));
}
// lo = fma(c.lo, r.hi, acc.lo); hi = fma(c.hi, r.hi, acc.hi)
__device__ __forceinline__ void pk_hi(f32x2 &acc, f32x2 c, f32x2 r) {
    asm("v_pk_fma_f32 %0, %1, %2, %0 op_sel:[0,1,0] op_sel_hi:[1,1,1]"
        : "+v"(acc) : "v"(c), "v"(r));
}

// ---------------- input MLP: 5 -> 128 -> 128 -> 64, writes cols 192..255 ----
__global__ void k_input(const float* __restrict__ x, const float* __restrict__ dn,
                        const float* __restrict__ w1, const float* __restrict__ b1,
                        const float* __restrict__ w2, const float* __restrict__ b2,
                        const float* __restrict__ w3, const float* __restrict__ b3,
                        float* __restrict__ Hout) {
    __shared__ float xs[8][5];
    __shared__ float t1[8][128];
    __shared__ float t2[8][128];
    int tid = threadIdx.x;            // 128 threads
    int p0 = blockIdx.x * 8;
    if (tid < 40) { int p = tid / 5, f = tid - p * 5; xs[p][f] = x[(p0 + p) * 5 + f] * dn[f]; }
    __syncthreads();
    int c = tid;
    {
        float bb = b1[c];
        #pragma unroll
        for (int p = 0; p < 8; p++) {
            float a = bb;
            #pragma unroll
            for (int f = 0; f < 5; f++) a += xs[p][f] * w1[f * 128 + c];
            t1[p][c] = fmaxf(a, 0.f);
        }
    }
    __syncthreads();
    {
        float acc[8];
        float bb = b2[c];
        #pragma unroll
        for (int p = 0; p < 8; p++) acc[p] = bb;
        for (int k = 0; k < 128; k++) {
            float w = w2[k * 128 + c];
            #pragma unroll
            for (int p = 0; p < 8; p++) acc[p] += t1[p][k] * w;
        }
        #pragma unroll
        for (int p = 0; p < 8; p++) t2[p][c] = fmaxf(acc[p], 0.f);
    }
    __syncthreads();
    if (c < 64) {
        float acc[8];
        float bb = b3[c];
        #pragma unroll
        for (int p = 0; p < 8; p++) acc[p] = bb;
        for (int k = 0; k < 128; k++) {
            float w = w3[k * 64 + c];
            #pragma unroll
            for (int p = 0; p < 8; p++) acc[p] += t2[p][k] * w;
        }
        #pragma unroll
        for (int p = 0; p < 8; p++) Hout[(p0 + p) * 256 + 192 + c] = fmaxf(acc[p], 0.f);
    }
}

// ---------------- per-conv weight prep: WUV = [(top-bot)*s | bot*s], cvec ----
__global__ void k_prep(const float* __restrict__ wa, const float* __restrict__ ba,
                       const float* __restrict__ g, const float* __restrict__ bB,
                       const float* __restrict__ m, const float* __restrict__ v,
                       int D, float* __restrict__ WUV, float* __restrict__ cvec) {
    int idx = blockIdx.x * 256 + threadIdx.x;
    if (idx < D * 192) {
        int k = idx / 192, col = idx - k * 192;
        int ch = (col < 96) ? col : col - 96;
        float s = g[ch] * rsqrtf(v[ch] + 1e-5f);
        float w = (col < 96) ? (wa[k * 96 + ch] - wa[(D + k) * 96 + ch]) : wa[(D + k) * 96 + ch];
        WUV[idx] = w * s;
    }
    if (blockIdx.x == 0 && threadIdx.x < 96) {
        int ch = threadIdx.x;
        float s = g[ch] * rsqrtf(v[ch] + 1e-5f);
        cvec[ch] = ba[ch] * s + (bB[ch] - m[ch] * s);
    }
}

// ---------------- per-batch feature transpose: Xt[b][d][1024] ----------------
__global__ void __launch_bounds__(256) k_tr(const float* __restrict__ Hout, int colOff, int D,
                                            float* __restrict__ Xt) {
    __shared__ float t[64][65];
    int tid = threadIdx.x;
    int d0 = blockIdx.x * 64, p0 = blockIdx.y * 64, b = blockIdx.z;
    int r4 = tid >> 6, c = tid & 63;
    #pragma unroll
    for (int k = 0; k < 16; k++) {
        int row = k * 4 + r4;
        t[row][c] = Hout[(size_t)(b * P + p0 + row) * 256 + colOff + d0 + c];
    }
    __syncthreads();
    #pragma unroll
    for (int k = 0; k < 16; k++) {
        int d = k * 4 + r4;
        Xt[((size_t)b * D + d0 + d) * 1024 + p0 + c] = t[c][d];
    }
}

// ---------------- row inverse norms (coalesced, from Xt) ----------------
__global__ void k_rn2(const float* __restrict__ Xt, int D, float* __restrict__ rn) {
    int p = blockIdx.x * 256 + threadIdx.x;
    if (p >= NPT) return;
    int b = p >> 10, pp = p & 1023;
    const float* base = Xt + (size_t)b * D * 1024 + pp;
    float ss = 0.f;
    for (int d = 0; d < D; d++) { float v = base[(size_t)d * 1024]; ss += v * v; }
    rn[p] = rsqrtf(ss + 1e-12f);
}

// ------ GEMM-style cosine-sim: 4 rows x 8 cands per thread, chunk=512 -------
// LDS: XiT (compute phase) and simtile (merge phase) share one buffer.
#define ST_LD 520

__device__ __forceinline__ unsigned long long packkey(float v, int q) {
    unsigned u = __float_as_uint(v);
    u = (u & 0x80000000u) ? ~u : (u | 0x80000000u);
    return ((unsigned long long)u << 32) | (unsigned)(1023 - q);
}

template<int D>
__global__ void __launch_bounds__(256) k_knn3(const float* __restrict__ Xt,
                                              const float* __restrict__ rn,
                                              unsigned long long* __restrict__ pkeys) {
    __shared__ __align__(16) float sbuf[16 * ST_LD];     // 33.3KB: XiT | simtile
    float* XiT = sbuf;                                   // [d][16 rows] (D*16 <= 3072 < 8320)
    float* simtile = sbuf;                               // [16 rows][ST_LD]
    int tid = threadIdx.x;
    int chunk = blockIdx.x & 1, rt = (blockIdx.x >> 1) & 63, b = blockIdx.x >> 7;
    int i0 = rt * 16, q0 = chunk * 512;
    int lane = tid & 63, w = tid >> 6;
    // stage XiT (row tile, transposed)
    for (int idx = tid; idx < 16 * D; idx += 256) {
        int d = idx >> 4, r = idx & 15;
        XiT[d * 16 + r] = Xt[((size_t)b * D + d) * 1024 + i0 + r];
    }
    __syncthreads();
    // ---- compute: thread = rows 4w..4w+3 x cands q0+8*lane..+7 ----
    const float* cvb = Xt + (size_t)b * D * 1024 + q0 + 8 * lane;
    f32x2 accA[4] = {}, accB[4] = {}, accC[4] = {}, accD[4] = {};
    #pragma unroll 4
    for (int d = 0; d < D; d++) {
        float4 cv0 = *(const float4*)(cvb + (size_t)d * 1024);
        float4 cv1 = *(const float4*)(cvb + (size_t)d * 1024 + 4);
        float4 rv = *(const float4*)(XiT + d * 16 + 4 * w);
        f32x2 cA = {cv0.x, cv0.y}, cB = {cv0.z, cv0.w};
        f32x2 cC = {cv1.x, cv1.y}, cD = {cv1.z, cv1.w};
        f32x2 rAB = {rv.x, rv.y}, rCD = {rv.z, rv.w};
        pk_lo(accA[0], cA, rAB); pk_lo(accB[0], cB, rAB); pk_lo(accC[0], cC, rAB); pk_lo(accD[0], cD, rAB);
        pk_hi(accA[1], cA, rAB); pk_hi(accB[1], cB, rAB); pk_hi(accC[1], cC, rAB); pk_hi(accD[1], cD, rAB);
        pk_lo(accA[2], cA, rCD); pk_lo(accB[2], cB, rCD); pk_lo(accC[2], cC, rCD); pk_lo(accD[2], cD, rCD);
        pk_hi(accA[3], cA, rCD); pk_hi(accB[3], cB, rCD); pk_hi(accC[3], cC, rCD); pk_hi(accD[3], cD, rCD);
    }
    __syncthreads();   // XiT dead after this; simtile may overwrite the buffer
    float4 rq0 = *(const float4*)(rn + b * P + q0 + 8 * lane);
    float4 rq1 = *(const float4*)(rn + b * P + q0 + 8 * lane + 4);
    int qg = q0 + 8 * lane;
    #pragma unroll
    for (int r = 0; r < 4; r++) {
        float rnir = rn[b * P + i0 + 4 * w + r];
        int ig = i0 + 4 * w + r;
        float4 v0, v1;
        v0.x = accA[r].x * rnir * rq0.x;
        v0.y = accA[r].y * rnir * rq0.y;
        v0.z = accB[r].x * rnir * rq0.z;
        v0.w = accB[r].y * rnir * rq0.w;
        v1.x = accC[r].x * rnir * rq1.x;
        v1.y = accC[r].y * rnir * rq1.y;
        v1.z = accD[r].x * rnir * rq1.z;
        v1.w = accD[r].y * rnir * rq1.w;
        if (qg + 0 == ig) v0.x = -1e9f;
        if (qg + 1 == ig) v0.y = -1e9f;
        if (qg + 2 == ig) v0.z = -1e9f;
        if (qg + 3 == ig) v0.w = -1e9f;
        if (qg + 4 == ig) v1.x = -1e9f;
        if (qg + 5 == ig) v1.y = -1e9f;
        if (qg + 6 == ig) v1.z = -1e9f;
        if (qg + 7 == ig) v1.w = -1e9f;
        *(float4*)(simtile + (4 * w + r) * ST_LD + 8 * lane) = v0;
        *(float4*)(simtile + (4 * w + r) * ST_LD + 8 * lane + 4) = v1;
    }
    __syncthreads();
    // ---- ballot-filter + blind-insert: 16-lane group per row, 8 tiles ----
    int g = lane >> 4, lane16 = lane & 15;
    int row = w * 4 + g;
    int sh = lane & 48;
    unsigned long long listkey = 0ull;
    for (int t = 0; t < 8; t++) {
        int qb = q0 + t * 64;
        unsigned long long c0 = packkey(simtile[row * ST_LD + t * 64 + lane16     ], qb + lane16);
        unsigned long long c1 = packkey(simtile[row * ST_LD + t * 64 + lane16 + 16], qb + lane16 + 16);
        unsigned long long c2 = packkey(simtile[row * ST_LD + t * 64 + lane16 + 32], qb + lane16 + 32);
        unsigned long long c3 = packkey(simtile[row * ST_LD + t * 64 + lane16 + 48], qb + lane16 + 48);
        unsigned long long lmin = __shfl(listkey, 15, 16);
        unsigned long long b0 = __ballot(c0 > lmin);
        unsigned long long b1 = __ballot(c1 > lmin);
        unsigned long long b2 = __ballot(c2 > lmin);
        unsigned long long b3 = __ballot(c3 > lmin);
        unsigned long long gm = ((b0 >> sh) & 0xFFFFull)
                              | (((b1 >> sh) & 0xFFFFull) << 16)
                              | (((b2 >> sh) & 0xFFFFull) << 32)
                              | (((b3 >> sh) & 0xFFFFull) << 48);
        // stale (too-small) candidates self-discard (pos==16 -> no-op)
        while (gm) {
            int pb = __builtin_ctzll(gm);
            gm &= gm - 1;
            int slot = pb >> 4, src = pb & 15;
            unsigned long long sel = (slot & 2) ? ((slot & 1) ? c3 : c2)
                                                : ((slot & 1) ? c1 : c0);
            unsigned long long mv = __shfl(sel, src, 16);
            unsigned long long bal = __ballot(listkey > mv);
            int pos = __popcll((bal >> sh) & 0xFFFFull);
            unsigned long long up = __shfl_up(listkey, 1, 16);
            if (lane16 == pos) listkey = mv;
            else if (lane16 > pos) listkey = up;
        }
    }
    pkeys[(((size_t)(b * P + i0 + row)) * NCH + chunk) * 16 + lane16] = listkey;
}

// ---- exact merge of per-chunk sorted top-16 lists -> final top-16 ----------
__global__ void __launch_bounds__(256) k_knn_merge(const unsigned long long* __restrict__ pkeys,
                                                   int* __restrict__ nbr) {
    int tid = threadIdx.x;
    int lane = tid & 63, w = tid >> 6;
    int g = lane >> 4, lane16 = lane & 15;
    int row = blockIdx.x * 16 + w * 4 + g;
    int sh = lane & 48;
    // chunk 0's list is already sorted descending across lane16
    unsigned long long listkey = pkeys[((size_t)row * NCH + 0) * 16 + lane16];
    #pragma unroll
    for (int s = 1; s < NCH; s++) {
        unsigned long long cand = pkeys[((size_t)row * NCH + s) * 16 + lane16];
        unsigned long long lmin = __shfl(listkey, 15, 16);
        unsigned long long bal = __ballot(cand > lmin);
        unsigned long long gm = (bal >> sh) & 0xFFFFull;
        while (gm) {
            int src = __builtin_ctzll(gm);
            gm &= gm - 1;
            unsigned long long mv = __shfl(cand, src, 16);
            unsigned long long bal2 = __ballot(listkey > mv);
            int pos = __popcll((bal2 >> sh) & 0xFFFFull);
            unsigned long long up = __shfl_up(listkey, 1, 16);
            if (lane16 == pos) listkey = mv;       // stale cand: pos==16 -> no-op
            else if (lane16 > pos) listkey = up;
        }
    }
    nbr[(size_t)row * KNN + lane16] = 1023 - (int)(listkey & 0xFFFFFFFFull);
}

// ---------------- UV projection: [16384, D] @ [D, 192] ----------------
__global__ void k_uv(const float* __restrict__ Hout, int colOff, int D,
                     const float* __restrict__ WUV, float* __restrict__ UV) {
    __shared__ __align__(16) float Xt[16 * 192];
    int tid = threadIdx.x;   // 192 threads
    int p0 = blockIdx.x * 16;
    for (int idx = tid; idx < 16 * D; idx += 192) {
        int r = idx / D, d = idx - r * D;
        Xt[r * 192 + d] = Hout[(p0 + r) * 256 + colOff + d];
    }
    __syncthreads();
    float acc[16];
    #pragma unroll
    for (int p = 0; p < 16; p++) acc[p] = 0.f;
    for (int k = 0; k < D; k += 4) {
        float w0 = WUV[(k + 0) * 192 + tid];
        float w1 = WUV[(k + 1) * 192 + tid];
        float w2 = WUV[(k + 2) * 192 + tid];
        float w3 = WUV[(k + 3) * 192 + tid];
        #pragma unroll
        for (int p = 0; p < 16; p++) {
            float4 xv = *(const float4*)(Xt + p * 192 + k);
            acc[p] += xv.x * w0;
            acc[p] += xv.y * w1;
            acc[p] += xv.z * w2;
            acc[p] += xv.w * w3;
        }
    }
    #pragma unroll
    for (int p = 0; p < 16; p++) UV[(size_t)(p0 + p) * 192 + tid] = acc[p];
}

// ------ per-edge message kernel: double-buffered msgs, 2-unrolled pipeline --
__global__ void __launch_bounds__(256, 4) k_edge(const float* __restrict__ UV, const int* __restrict__ nbr,
                                                 const float* __restrict__ wb, const float* __restrict__ bbv,
                                                 const float* __restrict__ cvec, int colOut,
                                                 float* __restrict__ Hout) {
    __shared__ __align__(16) f32x2 msgA[4][96];  // wave-private {fwd,rev}, buffer A
    __shared__ __align__(16) f32x2 msgB[4][96];  // buffer B (static distinct address)
    __shared__ float cvs[96];
    __shared__ float bbs[64];
    int tid = threadIdx.x;
    int w = tid >> 6, lane = tid & 63;
    float wreg[96];                              // wb column `lane` in registers
    #pragma unroll
    for (int k = 0; k < 96; k++) wreg[k] = wb[k * 64 + lane];
    if (tid < 96) cvs[tid] = cvec[tid];
    if (tid < 64) bbs[tid] = bbv[tid];
    int ifl = blockIdx.x * 4 + w;
    int b = ifl >> 10, i = ifl & 1023;
    const float* Ui = UV + (size_t)ifl * 192;
    float ui0 = Ui[lane];
    float ui1 = (lane < 32) ? Ui[64 + lane] : 0.f;
    float vi0 = Ui[96 + lane];
    float vi1 = (lane < 32) ? Ui[160 + lane] : 0.f;
    // hoist all 16 neighbor indices (lanes 0-15 authoritative, shfl-broadcast)
    int jv = nbr[ifl * KNN + (lane & 15)];
    // batched mutuality: lane l checks entries 4*(l&3)..+3 of knn(j_{l>>2})
    int jk = __shfl(jv, lane >> 2, 64);
    const int4* nb4p = (const int4*)(nbr + ((size_t)b * P + jk) * KNN + (lane & 3) * 4);
    int4 nb4 = *nb4p;
    bool hit = (nb4.x == i) | (nb4.y == i) | (nb4.z == i) | (nb4.w == i);
    unsigned long long mb = __ballot(hit);
    mb |= (mb >> 1); mb |= (mb >> 2);            // bit 4k = any of bits 4k..4k+3
    float accA = 0.f;
    __syncthreads();
    float bbl = bbs[lane];
    float cv0 = cvs[lane];
    float cv1 = (lane < 32) ? cvs[64 + lane] : 0.f;
    f32x2 ai0 = {ui0, vi0};      // loop-invariant packed centers
    f32x2 ai1 = {ui1, vi1};
    f32x2 cc0 = {cv0, cv0};
    f32x2 cc1 = {cv1, cv1};
    // packed message write: {fwd,rev} = relu({ui,vi} + {Vj,Uj} + {cv,cv})
    auto MSG = [&](f32x2* mrow, float cu0, float cu1, float cw0, float cw1) {
        f32x2 s0 = {cw0, cu0};
        f32x2 m0 = ai0 + s0 + cc0;
        m0.x = fmaxf(m0.x, 0.f);
        m0.y = fmaxf(m0.y, 0.f);
        mrow[lane] = m0;
        if (lane < 32) {
            f32x2 s1 = {cw1, cu1};
            f32x2 m1 = ai1 + s1 + cc1;
            m1.x = fmaxf(m1.x, 0.f);
            m1.y = fmaxf(m1.y, 0.f);
            mrow[64 + lane] = m1;
        }
    };
    // packed dual GEMV, 4 independent chains (depth 24 each, issue-bound)
    auto GEMV = [&](const f32x2* mrowc) -> f32x2 {
        const float4* mq = (const float4*)mrowc;
        f32x2 t0 = {bbl, bbl};
        f32x2 t1 = {0.f, 0.f};
        f32x2 t2 = {0.f, 0.f};
        f32x2 t3 = {0.f, 0.f};
        #pragma unroll
        for (int k8 = 0; k8 < 12; k8++) {
            float4 qa = mq[4 * k8 + 0];
            float4 qb = mq[4 * k8 + 1];
            float4 qc = mq[4 * k8 + 2];
            float4 qd = mq[4 * k8 + 3];
            t0 += (f32x2){qa.x, qa.y} * (f32x2){wreg[8 * k8 + 0], wreg[8 * k8 + 0]};
            t0 += (f32x2){qa.z, qa.w} * (f32x2){wreg[8 * k8 + 1], wreg[8 * k8 + 1]};
            t1 += (f32x2){qb.x, qb.y} * (f32x2){wreg[8 * k8 + 2], wreg[8 * k8 + 2]};
            t1 += (f32x2){qb.z, qb.w} * (f32x2){wreg[8 * k8 + 3], wreg[8 * k8 + 3]};
            t2 += (f32x2){qc.x, qc.y} * (f32x2){wreg[8 * k8 + 4], wreg[8 * k8 + 4]};
            t2 += (f32x2){qc.z, qc.w} * (f32x2){wreg[8 * k8 + 5], wreg[8 * k8 + 5]};
            t3 += (f32x2){qd.x, qd.y} * (f32x2){wreg[8 * k8 + 6], wreg[8 * k8 + 6]};
            t3 += (f32x2){qd.z, qd.w} * (f32x2){wreg[8 * k8 + 7], wreg[8 * k8 + 7]};
        }
        return (t0 + t1) + (t2 + t3);
    };
    // ---- software pipeline: msgs for nbr0 in A; U/V for nbr1 staged --------
    int jf0 = b * P + __shfl(jv, 0, 64);
    {
        const float* U0 = UV + (size_t)jf0 * 192;
        float au0 = U0[lane];
        float au1 = (lane < 32) ? U0[64 + lane] : 0.f;
        float av0 = U0[96 + lane];
        float av1 = (lane < 32) ? U0[160 + lane] : 0.f;
        MSG(msgA[w], au0, au1, av0, av1);
    }
    int jf1 = b * P + __shfl(jv, 1, 64);
    float bu0, bu1, bv0, bv1;
    {
        const float* U1 = UV + (size_t)jf1 * 192;
        bu0 = U1[lane];
        bu1 = (lane < 32) ? U1[64 + lane] : 0.f;
        bv0 = U1[96 + lane];
        bv1 = (lane < 32) ? U1[160 + lane] : 0.f;
    }
    float au0, au1, av0, av1;
    #pragma unroll
    for (int kk = 0; kk < KNN; kk += 2) {
        int jfcA = jf0;
        if (kk + 2 < KNN) {                      // gather kk+2 early
            jf0 = b * P + __shfl(jv, kk + 2, 64);
            const float* Un = UV + (size_t)jf0 * 192;
            au0 = Un[lane];
            au1 = (lane < 32) ? Un[64 + lane] : 0.f;
            av0 = Un[96 + lane];
            av1 = (lane < 32) ? Un[160 + lane] : 0.f;
        }
        MSG(msgB[w], bu0, bu1, bv0, bv1);        // messages for kk+1 -> B
        f32x2 ttA = GEMV(msgA[w]);               // results for kk (reads A)
        accA += fmaxf(ttA.x, 0.f);
        if (!((mb >> (4 * kk)) & 1))
            atomicAdd(&Hout[(size_t)jfcA * 256 + colOut + lane], fmaxf(ttA.y, 0.f));
        int jfcB = jf1;
        if (kk + 3 < KNN) {                      // gather kk+3 early
            jf1 = b * P + __shfl(jv, kk + 3, 64);
            const float* Un = UV + (size_t)jf1 * 192;
            bu0 = Un[lane];
            bu1 = (lane < 32) ? Un[64 + lane] : 0.f;
            bv0 = Un[96 + lane];
            bv1 = (lane < 32) ? Un[160 + lane] : 0.f;
        }
        if (kk + 2 < KNN)
            MSG(msgA[w], au0, au1, av0, av1);    // messages for kk+2 -> A
        f32x2 ttB = GEMV(msgB[w]);               // results for kk+1 (reads B)
        accA += fmaxf(ttB.x, 0.f);
        if (!((mb >> (4 * (kk + 1))) & 1))
            atomicAdd(&Hout[(size_t)jfcB * 256 + colOut + lane], fmaxf(ttB.y, 0.f));
    }
    atomicAdd(&Hout[(size_t)ifl * 256 + colOut + lane], accA);
}

// ---------------- global max pool (partial) ----------------
__global__ void k_pool(const float* __restrict__ Hout, float* __restrict__ part) {
    int tid = threadIdx.x;
    int b = blockIdx.x >> 4, pt = blockIdx.x & 15;
    float mv = -1e30f;
    for (int p = pt * 64; p < pt * 64 + 64; p++)
        mv = fmaxf(mv, Hout[(size_t)(b * P + p) * 256 + tid]);
    part[(b * 16 + pt) * 256 + tid] = mv;
}

// ---------------- final reduce + output MLP ----------------
__global__ void k_out(const float* __restrict__ part,
                      const float* __restrict__ w1, const float* __restrict__ b1,
                      const float* __restrict__ w2, const float* __restrict__ b2,
                      const float* __restrict__ w3, const float* __restrict__ b3,
                      float* __restrict__ out) {
    __shared__ float pooled[256];
    __shared__ float r1[128];
    __shared__ float r2[32];
    int tid = threadIdx.x, b = blockIdx.x;
    float mv = -1e30f;
    for (int t = 0; t < 16; t++) mv = fmaxf(mv, part[(b * 16 + t) * 256 + tid]);
    pooled[tid] = mv;
    __syncthreads();
    if (tid < 128) {
        float a = b1[tid];
        for (int k = 0; k < 256; k++) a += pooled[k] * w1[k * 128 + tid];
        r1[tid] = fmaxf(a, 0.f);
    }
    __syncthreads();
    if (tid < 32) {
        float a = b2[tid];
        for (int k = 0; k < 128; k++) a += r1[k] * w2[k * 32 + tid];
        r2[tid] = fmaxf(a, 0.f);
    }
    __syncthreads();
    if (tid == 0) {
        float a = b3[0];
        for (int k = 0; k < 32; k++) a += r2[k] * w3[k];
        out[b] = a;
    }
}

extern "C" void kernel_launch(void* const* d_in, const int* in_sizes, int n_in,
                              void* d_out, int out_size, void* d_ws, size_t ws_size,
                              hipStream_t stream) {
    const float* x  = (const float*)d_in[0];
    const float* dn = (const float*)d_in[1];
    float* out = (float*)d_out;
    float* Hout = out + 16;           // [16384][256] feature/output buffer
    float* ws = (float*)d_ws;
    float* UV   = ws + WS_UV;
    float* rn   = ws + WS_RN;
    int*   nbr  = (int*)(ws + WS_NBR);
    float* WUV  = ws + WS_WUV;
    float* cvec = ws + WS_CVEC;
    float* part = ws + WS_PART;
    float* Xt   = ws + WS_XT;
    unsigned long long* pkeys = (unsigned long long*)UV;   // aliased: dead before k_uv

    hipMemsetAsync(d_out, 0, (size_t)out_size * sizeof(float), stream);

    k_input<<<2048, 128, 0, stream>>>(x, dn,
        (const float*)d_in[2], (const float*)d_in[3],
        (const float*)d_in[4], (const float*)d_in[5],
        (const float*)d_in[6], (const float*)d_in[7], Hout);

    const int convOff[3] = {192, 128, 64};   // input column offset
    const int convD[3]   = {64, 128, 192};   // input feature width
    const int convOut[3] = {128, 64, 0};     // output column offset
    for (int c = 0; c < 3; c++) {
        int pb = 8 + c * 8;
        const float* wa  = (const float*)d_in[pb + 0];
        const float* ba  = (const float*)d_in[pb + 1];
        const float* g   = (const float*)d_in[pb + 2];
        const float* bB  = (const float*)d_in[pb + 3];
        const float* m   = (const float*)d_in[pb + 4];
        const float* v   = (const float*)d_in[pb + 5];
        const float* wb  = (const float*)d_in[pb + 6];
        const float* bbv = (const float*)d_in[pb + 7];
        int D = convD[c], off = convOff[c], co = convOut[c];
        k_prep<<<(D * 192 + 255) / 256, 256, 0, stream>>>(wa, ba, g, bB, m, v, D, WUV, cvec);
        k_tr<<<dim3(D / 64, P / 64, B), 256, 0, stream>>>(Hout, off, D, Xt);
        k_rn2<<<64, 256, 0, stream>>>(Xt, D, rn);
        if (c == 0)      k_knn3<64><<<2048, 256, 0, stream>>>(Xt, rn, pkeys);
        else if (c == 1) k_knn3<128><<<2048, 256, 0, stream>>>(Xt, rn, pkeys);
        else             k_knn3<192><<<2048, 256, 0, stream>>>(Xt, rn, pkeys);
        k_knn_merge<<<1024, 256, 0, stream>>>(pkeys, nbr);
        k_uv<<<1024, 192, 0, stream>>>(Hout, off, D, WUV, UV);
        k_edge<<<4096, 256, 0, stream>>>(UV, nbr, wb, bbv, cvec, co, Hout);
    }

    k_pool<<<256, 256, 0, stream>>>(Hout, part);
    k_out<<<16, 256, 0, stream>>>(part,
        (const float*)d_in[32], (const float*)d_in[33],
        (const float*)d_in[34], (const float*)d_in[35],
        (const float*)d_in[36], (const float*)d_in[37], out);
}

// Round 19
// 1109.396 us; speedup vs baseline: 3.8576x; 3.8576x over previous
//
#include <hip/hip_runtime.h>
#include <hip/hip_bf16.h>

#define B 16
#define P 1024
#define NPT 16384   // B*P
#define KNN 16
#define MID 96
#define HD 64

// ws layout (in floats)
#define WS_UV   0                        // NPT*192  (aliased as pkeys: NPT*2*16 u64 = 4.2MB < 12.58MB)
#define WS_RN   (WS_UV + NPT*192)        // NPT
#define WS_NBR  (WS_RN + NPT)            // NPT*KNN ints
#define WS_WUV  (WS_NBR + NPT*KNN)       // up to 192*192
#define WS_CVEC (WS_WUV + 192*192)       // 96
#define WS_PART (WS_CVEC + 96)           // B*16*256
#define WS_XT   (WS_PART + 16*16*256)    // B*192*1024 floats (transposed features)

#define NCH 2        // chunk lists per row (512 cands per chunk)

typedef float f32x2 __attribute__((ext_vector_type(2)));

// VOP3P packed fma with op_sel broadcast of one src1 half (no splat movs).
// lo = fma(c.lo, r.lo, acc.lo); hi = fma(c.hi, r.lo, acc.hi)
__device__ __forceinline__ void pk_lo(f32x2 &acc, f32x2 c, f32x2 r) {
    asm("v_pk_fma_f32 %0, %1, %2, %0 op_sel:[0,0,0] op_sel_hi:[1,0,1]"
        : "+v"(acc) : "v"(c), "v"(r));
}
// lo = fma(c.lo, r.hi, acc.lo); hi = fma(c.hi, r.hi, acc.hi)
__device__ __forceinline__ void pk_hi(f32x2 &acc, f32x2 c, f32x2 r) {
    asm("v_pk_fma_f32 %0, %1, %2, %0 op_sel:[0,1,0] op_sel_hi:[1,1,1]"
        : "+v"(acc) : "v"(c), "v"(r));
}

// ---------------- input MLP: 5 -> 128 -> 128 -> 64, writes cols 192..255 ----
__global__ void k_input(const float* __restrict__ x, const float* __restrict__ dn,
                        const float* __restrict__ w1, const float* __restrict__ b1,
                        const float* __restrict__ w2, const float* __restrict__ b2,
                        const float* __restrict__ w3, const float* __restrict__ b3,
                        float* __restrict__ Hout) {
    __shared__ float xs[8][5];
    __shared__ float t1[8][128];
    __shared__ float t2[8][128];
    int tid = threadIdx.x;            // 128 threads
    int p0 = blockIdx.x * 8;
    if (tid < 40) { int p = tid / 5, f = tid - p * 5; xs[p][f] = x[(p0 + p) * 5 + f] * dn[f]; }
    __syncthreads();
    int c = tid;
    {
        float bb = b1[c];
        #pragma unroll
        for (int p = 0; p < 8; p++) {
            float a = bb;
            #pragma unroll
            for (int f = 0; f < 5; f++) a += xs[p][f] * w1[f * 128 + c];
            t1[p][c] = fmaxf(a, 0.f);
        }
    }
    __syncthreads();
    {
        float acc[8];
        float bb = b2[c];
        #pragma unroll
        for (int p = 0; p < 8; p++) acc[p] = bb;
        for (int k = 0; k < 128; k++) {
            float w = w2[k * 128 + c];
            #pragma unroll
            for (int p = 0; p < 8; p++) acc[p] += t1[p][k] * w;
        }
        #pragma unroll
        for (int p = 0; p < 8; p++) t2[p][c] = fmaxf(acc[p], 0.f);
    }
    __syncthreads();
    if (c < 64) {
        float acc[8];
        float bb = b3[c];
        #pragma unroll
        for (int p = 0; p < 8; p++) acc[p] = bb;
        for (int k = 0; k < 128; k++) {
            float w = w3[k * 64 + c];
            #pragma unroll
            for (int p = 0; p < 8; p++) acc[p] += t2[p][k] * w;
        }
        #pragma unroll
        for (int p = 0; p < 8; p++) Hout[(p0 + p) * 256 + 192 + c] = fmaxf(acc[p], 0.f);
    }
}

// ---------------- per-conv weight prep: WUV = [(top-bot)*s | bot*s], cvec ----
__global__ void k_prep(const float* __restrict__ wa, const float* __restrict__ ba,
                       const float* __restrict__ g, const float* __restrict__ bB,
                       const float* __restrict__ m, const float* __restrict__ v,
                       int D, float* __restrict__ WUV, float* __restrict__ cvec) {
    int idx = blockIdx.x * 256 + threadIdx.x;
    if (idx < D * 192) {
        int k = idx / 192, col = idx - k * 192;
        int ch = (col < 96) ? col : col - 96;
        float s = g[ch] * rsqrtf(v[ch] + 1e-5f);
        float w = (col < 96) ? (wa[k * 96 + ch] - wa[(D + k) * 96 + ch]) : wa[(D + k) * 96 + ch];
        WUV[idx] = w * s;
    }
    if (blockIdx.x == 0 && threadIdx.x < 96) {
        int ch = threadIdx.x;
        float s = g[ch] * rsqrtf(v[ch] + 1e-5f);
        cvec[ch] = ba[ch] * s + (bB[ch] - m[ch] * s);
    }
}

// ---------------- per-batch feature transpose: Xt[b][d][1024] ----------------
__global__ void __launch_bounds__(256) k_tr(const float* __restrict__ Hout, int colOff, int D,
                                            float* __restrict__ Xt) {
    __shared__ float t[64][65];
    int tid = threadIdx.x;
    int d0 = blockIdx.x * 64, p0 = blockIdx.y * 64, b = blockIdx.z;
    int r4 = tid >> 6, c = tid & 63;
    #pragma unroll
    for (int k = 0; k < 16; k++) {
        int row = k * 4 + r4;
        t[row][c] = Hout[(size_t)(b * P + p0 + row) * 256 + colOff + d0 + c];
    }
    __syncthreads();
    #pragma unroll
    for (int k = 0; k < 16; k++) {
        int d = k * 4 + r4;
        Xt[((size_t)b * D + d0 + d) * 1024 + p0 + c] = t[c][d];
    }
}

// ---------------- row inverse norms (coalesced, from Xt) ----------------
__global__ void k_rn2(const float* __restrict__ Xt, int D, float* __restrict__ rn) {
    int p = blockIdx.x * 256 + threadIdx.x;
    if (p >= NPT) return;
    int b = p >> 10, pp = p & 1023;
    const float* base = Xt + (size_t)b * D * 1024 + pp;
    float ss = 0.f;
    for (int d = 0; d < D; d++) { float v = base[(size_t)d * 1024]; ss += v * v; }
    rn[p] = rsqrtf(ss + 1e-12f);
}

// ------ GEMM-style cosine-sim: 4 rows x 8 cands per thread, chunk=512 -------
// LDS: XiT (compute phase) and simtile (merge phase) share one buffer.
#define ST_LD 520

__device__ __forceinline__ unsigned long long packkey(float v, int q) {
    unsigned u = __float_as_uint(v);
    u = (u & 0x80000000u) ? ~u : (u | 0x80000000u);
    return ((unsigned long long)u << 32) | (unsigned)(1023 - q);
}

template<int D>
__global__ void __launch_bounds__(256) k_knn3(const float* __restrict__ Xt,
                                              const float* __restrict__ rn,
                                              unsigned long long* __restrict__ pkeys) {
    __shared__ __align__(16) float sbuf[16 * ST_LD];     // 33.3KB: XiT | simtile
    float* XiT = sbuf;                                   // [d][16 rows] (D*16 <= 3072 < 8320)
    float* simtile = sbuf;                               // [16 rows][ST_LD]
    int tid = threadIdx.x;
    int chunk = blockIdx.x & 1, rt = (blockIdx.x >> 1) & 63, b = blockIdx.x >> 7;
    int i0 = rt * 16, q0 = chunk * 512;
    int lane = tid & 63, w = tid >> 6;
    // stage XiT (row tile, transposed)
    for (int idx = tid; idx < 16 * D; idx += 256) {
        int d = idx >> 4, r = idx & 15;
        XiT[d * 16 + r] = Xt[((size_t)b * D + d) * 1024 + i0 + r];
    }
    __syncthreads();
    // ---- compute: thread = rows 4w..4w+3 x cands q0+8*lane..+7 ----
    const float* cvb = Xt + (size_t)b * D * 1024 + q0 + 8 * lane;
    f32x2 accA[4] = {}, accB[4] = {}, accC[4] = {}, accD[4] = {};
    #pragma unroll 4
    for (int d = 0; d < D; d++) {
        float4 cv0 = *(const float4*)(cvb + (size_t)d * 1024);
        float4 cv1 = *(const float4*)(cvb + (size_t)d * 1024 + 4);
        float4 rv = *(const float4*)(XiT + d * 16 + 4 * w);
        f32x2 cA = {cv0.x, cv0.y}, cB = {cv0.z, cv0.w};
        f32x2 cC = {cv1.x, cv1.y}, cD = {cv1.z, cv1.w};
        f32x2 rAB = {rv.x, rv.y}, rCD = {rv.z, rv.w};
        pk_lo(accA[0], cA, rAB); pk_lo(accB[0], cB, rAB); pk_lo(accC[0], cC, rAB); pk_lo(accD[0], cD, rAB);
        pk_hi(accA[1], cA, rAB); pk_hi(accB[1], cB, rAB); pk_hi(accC[1], cC, rAB); pk_hi(accD[1], cD, rAB);
        pk_lo(accA[2], cA, rCD); pk_lo(accB[2], cB, rCD); pk_lo(accC[2], cC, rCD); pk_lo(accD[2], cD, rCD);
        pk_hi(accA[3], cA, rCD); pk_hi(accB[3], cB, rCD); pk_hi(accC[3], cC, rCD); pk_hi(accD[3], cD, rCD);
    }
    __syncthreads();   // XiT dead after this; simtile may overwrite the buffer
    float4 rq0 = *(const float4*)(rn + b * P + q0 + 8 * lane);
    float4 rq1 = *(const float4*)(rn + b * P + q0 + 8 * lane + 4);
    int qg = q0 + 8 * lane;
    #pragma unroll
    for (int r = 0; r < 4; r++) {
        float rnir = rn[b * P + i0 + 4 * w + r];
        int ig = i0 + 4 * w + r;
        float4 v0, v1;
        v0.x = accA[r].x * rnir * rq0.x;
        v0.y = accA[r].y * rnir * rq0.y;
        v0.z = accB[r].x * rnir * rq0.z;
        v0.w = accB[r].y * rnir * rq0.w;
        v1.x = accC[r].x * rnir * rq1.x;
        v1.y = accC[r].y * rnir * rq1.y;
        v1.z = accD[r].x * rnir * rq1.z;
        v1.w = accD[r].y * rnir * rq1.w;
        if (qg + 0 == ig) v0.x = -1e9f;
        if (qg + 1 == ig) v0.y = -1e9f;
        if (qg + 2 == ig) v0.z = -1e9f;
        if (qg + 3 == ig) v0.w = -1e9f;
        if (qg + 4 == ig) v1.x = -1e9f;
        if (qg + 5 == ig) v1.y = -1e9f;
        if (qg + 6 == ig) v1.z = -1e9f;
        if (qg + 7 == ig) v1.w = -1e9f;
        *(float4*)(simtile + (4 * w + r) * ST_LD + 8 * lane) = v0;
        *(float4*)(simtile + (4 * w + r) * ST_LD + 8 * lane + 4) = v1;
    }
    __syncthreads();
    // ---- ballot-filter + blind-insert: 16-lane group per row, 8 tiles ----
    int g = lane >> 4, lane16 = lane & 15;
    int row = w * 4 + g;
    int sh = lane & 48;
    unsigned long long listkey = 0ull;
    for (int t = 0; t < 8; t++) {
        int qb = q0 + t * 64;
        unsigned long long c0 = packkey(simtile[row * ST_LD + t * 64 + lane16     ], qb + lane16);
        unsigned long long c1 = packkey(simtile[row * ST_LD + t * 64 + lane16 + 16], qb + lane16 + 16);
        unsigned long long c2 = packkey(simtile[row * ST_LD + t * 64 + lane16 + 32], qb + lane16 + 32);
        unsigned long long c3 = packkey(simtile[row * ST_LD + t * 64 + lane16 + 48], qb + lane16 + 48);
        unsigned long long lmin = __shfl(listkey, 15, 16);
        unsigned long long b0 = __ballot(c0 > lmin);
        unsigned long long b1 = __ballot(c1 > lmin);
        unsigned long long b2 = __ballot(c2 > lmin);
        unsigned long long b3 = __ballot(c3 > lmin);
        unsigned long long gm = ((b0 >> sh) & 0xFFFFull)
                              | (((b1 >> sh) & 0xFFFFull) << 16)
                              | (((b2 >> sh) & 0xFFFFull) << 32)
                              | (((b3 >> sh) & 0xFFFFull) << 48);
        // stale (too-small) candidates self-discard (pos==16 -> no-op)
        while (gm) {
            int pb = __builtin_ctzll(gm);
            gm &= gm - 1;
            int slot = pb >> 4, src = pb & 15;
            unsigned long long sel = (slot & 2) ? ((slot & 1) ? c3 : c2)
                                                : ((slot & 1) ? c1 : c0);
            unsigned long long mv = __shfl(sel, src, 16);
            unsigned long long bal = __ballot(listkey > mv);
            int pos = __popcll((bal >> sh) & 0xFFFFull);
            unsigned long long up = __shfl_up(listkey, 1, 16);
            if (lane16 == pos) listkey = mv;
            else if (lane16 > pos) listkey = up;
        }
    }
    pkeys[(((size_t)(b * P + i0 + row)) * NCH + chunk) * 16 + lane16] = listkey;
}

// ---- exact merge of per-chunk sorted top-16 lists -> final top-16 ----------
__global__ void __launch_bounds__(256) k_knn_merge(const unsigned long long* __restrict__ pkeys,
                                                   int* __restrict__ nbr) {
    int tid = threadIdx.x;
    int lane = tid & 63, w = tid >> 6;
    int g = lane >> 4, lane16 = lane & 15;
    int row = blockIdx.x * 16 + w * 4 + g;
    int sh = lane & 48;
    // chunk 0's list is already sorted descending across lane16
    unsigned long long listkey = pkeys[((size_t)row * NCH + 0) * 16 + lane16];
    #pragma unroll
    for (int s = 1; s < NCH; s++) {
        unsigned long long cand = pkeys[((size_t)row * NCH + s) * 16 + lane16];
        unsigned long long lmin = __shfl(listkey, 15, 16);
        unsigned long long bal = __ballot(cand > lmin);
        unsigned long long gm = (bal >> sh) & 0xFFFFull;
        while (gm) {
            int src = __builtin_ctzll(gm);
            gm &= gm - 1;
            unsigned long long mv = __shfl(cand, src, 16);
            unsigned long long bal2 = __ballot(listkey > mv);
            int pos = __popcll((bal2 >> sh) & 0xFFFFull);
            unsigned long long up = __shfl_up(listkey, 1, 16);
            if (lane16 == pos) listkey = mv;       // stale cand: pos==16 -> no-op
            else if (lane16 > pos) listkey = up;
        }
    }
    nbr[(size_t)row * KNN + lane16] = 1023 - (int)(listkey & 0xFFFFFFFFull);
}

// ---------------- UV projection: [16384, D] @ [D, 192] ----------------
__global__ void k_uv(const float* __restrict__ Hout, int colOff, int D,
                     const float* __restrict__ WUV, float* __restrict__ UV) {
    __shared__ __align__(16) float Xt[16 * 192];
    int tid = threadIdx.x;   // 192 threads
    int p0 = blockIdx.x * 16;
    for (int idx = tid; idx < 16 * D; idx += 192) {
        int r = idx / D, d = idx - r * D;
        Xt[r * 192 + d] = Hout[(p0 + r) * 256 + colOff + d];
    }
    __syncthreads();
    float acc[16];
    #pragma unroll
    for (int p = 0; p < 16; p++) acc[p] = 0.f;
    for (int k = 0; k < D; k += 4) {
        float w0 = WUV[(k + 0) * 192 + tid];
        float w1 = WUV[(k + 1) * 192 + tid];
        float w2 = WUV[(k + 2) * 192 + tid];
        float w3 = WUV[(k + 3) * 192 + tid];
        #pragma unroll
        for (int p = 0; p < 16; p++) {
            float4 xv = *(const float4*)(Xt + p * 192 + k);
            acc[p] += xv.x * w0;
            acc[p] += xv.y * w1;
            acc[p] += xv.z * w2;
            acc[p] += xv.w * w3;
        }
    }
    #pragma unroll
    for (int p = 0; p < 16; p++) UV[(size_t)(p0 + p) * 192 + tid] = acc[p];
}

// ------ per-edge message kernel: packed fwd/rev GEMV, 4 independent chains --
__global__ void __launch_bounds__(256) k_edge(const float* __restrict__ UV, const int* __restrict__ nbr,
                                              const float* __restrict__ wb, const float* __restrict__ bbv,
                                              const float* __restrict__ cvec, int colOut,
                                              float* __restrict__ Hout) {
    __shared__ __align__(16) f32x2 msg2[4][96];  // wave-private {fwd,rev} per channel
    __shared__ float cvs[96];
    __shared__ float bbs[64];
    int tid = threadIdx.x;
    int w = tid >> 6, lane = tid & 63;
    float wreg[96];                              // wb column `lane` in registers
    #pragma unroll
    for (int k = 0; k < 96; k++) wreg[k] = wb[k * 64 + lane];
    if (tid < 96) cvs[tid] = cvec[tid];
    if (tid < 64) bbs[tid] = bbv[tid];
    int ifl = blockIdx.x * 4 + w;
    int b = ifl >> 10, i = ifl & 1023;
    const float* Ui = UV + (size_t)ifl * 192;
    float ui0 = Ui[lane];
    float ui1 = (lane < 32) ? Ui[64 + lane] : 0.f;
    float vi0 = Ui[96 + lane];
    float vi1 = (lane < 32) ? Ui[160 + lane] : 0.f;
    // hoist all 16 neighbor indices (lanes 0-15 authoritative, shfl-broadcast)
    int jv = nbr[ifl * KNN + (lane & 15)];
    // batched mutuality: lane l checks entries 4*(l&3)..+3 of knn(j_{l>>2})
    int jk = __shfl(jv, lane >> 2, 64);
    const int4* nb4p = (const int4*)(nbr + ((size_t)b * P + jk) * KNN + (lane & 3) * 4);
    int4 nb4 = *nb4p;
    bool hit = (nb4.x == i) | (nb4.y == i) | (nb4.z == i) | (nb4.w == i);
    unsigned long long mb = __ballot(hit);
    mb |= (mb >> 1); mb |= (mb >> 2);            // bit 4k = any of bits 4k..4k+3
    float accA = 0.f;
    __syncthreads();
    float bbl = bbs[lane];
    float cv0 = cvs[lane];
    float cv1 = (lane < 32) ? cvs[64 + lane] : 0.f;
    f32x2* mrow = msg2[w];
    const float4* mq = (const float4*)mrow;
    f32x2 ai0 = {ui0, vi0};      // loop-invariant packed centers
    f32x2 ai1 = {ui1, vi1};
    f32x2 cc0 = {cv0, cv0};
    f32x2 cc1 = {cv1, cv1};
    // prefetch neighbor 0's U/V rows
    int jf = b * P + __shfl(jv, 0, 64);
    const float* Uj = UV + (size_t)jf * 192;
    float pu0 = Uj[lane];
    float pu1 = (lane < 32) ? Uj[64 + lane] : 0.f;
    float pv0 = Uj[96 + lane];
    float pv1 = (lane < 32) ? Uj[160 + lane] : 0.f;
    for (int kk = 0; kk < KNN; kk++) {
        float cu0 = pu0, cu1 = pu1, cw0 = pv0, cw1 = pv1;
        int jfc = jf;
        if (kk + 1 < KNN) {                      // issue next gather early (G7)
            jf = b * P + __shfl(jv, kk + 1, 64);
            const float* Un = UV + (size_t)jf * 192;
            pu0 = Un[lane];
            pu1 = (lane < 32) ? Un[64 + lane] : 0.f;
            pv0 = Un[96 + lane];
            pv1 = (lane < 32) ? Un[160 + lane] : 0.f;
        }
        // packed messages: {fwd,rev} = relu({ui,vi} + {Vj,Uj} + {cv,cv})
        {
            f32x2 s0 = {cw0, cu0};
            f32x2 m0 = ai0 + s0 + cc0;
            m0.x = fmaxf(m0.x, 0.f);
            m0.y = fmaxf(m0.y, 0.f);
            mrow[lane] = m0;
            if (lane < 32) {
                f32x2 s1 = {cw1, cu1};
                f32x2 m1 = ai1 + s1 + cc1;
                m1.x = fmaxf(m1.x, 0.f);
                m1.y = fmaxf(m1.y, 0.f);
                mrow[64 + lane] = m1;
            }
        }
        // packed dual GEMV, 4 INDEPENDENT chains (depth 24 each, issue-bound)
        f32x2 t0 = {bbl, bbl};
        f32x2 t1 = {0.f, 0.f};
        f32x2 t2 = {0.f, 0.f};
        f32x2 t3 = {0.f, 0.f};
        #pragma unroll
        for (int k8 = 0; k8 < 12; k8++) {
            float4 qa = mq[4 * k8 + 0];          // {fwd,rev} x 2 channels each
            float4 qb = mq[4 * k8 + 1];
            float4 qc = mq[4 * k8 + 2];
            float4 qd = mq[4 * k8 + 3];
            t0 += (f32x2){qa.x, qa.y} * (f32x2){wreg[8 * k8 + 0], wreg[8 * k8 + 0]};
            t0 += (f32x2){qa.z, qa.w} * (f32x2){wreg[8 * k8 + 1], wreg[8 * k8 + 1]};
            t1 += (f32x2){qb.x, qb.y} * (f32x2){wreg[8 * k8 + 2], wreg[8 * k8 + 2]};
            t1 += (f32x2){qb.z, qb.w} * (f32x2){wreg[8 * k8 + 3], wreg[8 * k8 + 3]};
            t2 += (f32x2){qc.x, qc.y} * (f32x2){wreg[8 * k8 + 4], wreg[8 * k8 + 4]};
            t2 += (f32x2){qc.z, qc.w} * (f32x2){wreg[8 * k8 + 5], wreg[8 * k8 + 5]};
            t3 += (f32x2){qd.x, qd.y} * (f32x2){wreg[8 * k8 + 6], wreg[8 * k8 + 6]};
            t3 += (f32x2){qd.z, qd.w} * (f32x2){wreg[8 * k8 + 7], wreg[8 * k8 + 7]};
        }
        f32x2 tt = (t0 + t1) + (t2 + t3);
        accA += fmaxf(tt.x, 0.f);
        if (!((mb >> (4 * kk)) & 1))
            atomicAdd(&Hout[(size_t)jfc * 256 + colOut + lane], fmaxf(tt.y, 0.f));
    }
    atomicAdd(&Hout[(size_t)ifl * 256 + colOut + lane], accA);
}

// ---------------- global max pool (partial) ----------------
__global__ void k_pool(const float* __restrict__ Hout, float* __restrict__ part) {
    int tid = threadIdx.x;
    int b = blockIdx.x >> 4, pt = blockIdx.x & 15;
    float mv = -1e30f;
    for (int p = pt * 64; p < pt * 64 + 64; p++)
        mv = fmaxf(mv, Hout[(size_t)(b * P + p) * 256 + tid]);
    part[(b * 16 + pt) * 256 + tid] = mv;
}

// ---------------- final reduce + output MLP ----------------
__global__ void k_out(const float* __restrict__ part,
                      const float* __restrict__ w1, const float* __restrict__ b1,
                      const float* __restrict__ w2, const float* __restrict__ b2,
                      const float* __restrict__ w3, const float* __restrict__ b3,
                      float* __restrict__ out) {
    __shared__ float pooled[256];
    __shared__ float r1[128];
    __shared__ float r2[32];
    int tid = threadIdx.x, b = blockIdx.x;
    float mv = -1e30f;
    for (int t = 0; t < 16; t++) mv = fmaxf(mv, part[(b * 16 + t) * 256 + tid]);
    pooled[tid] = mv;
    __syncthreads();
    if (tid < 128) {
        float a = b1[tid];
        for (int k = 0; k < 256; k++) a += pooled[k] * w1[k * 128 + tid];
        r1[tid] = fmaxf(a, 0.f);
    }
    __syncthreads();
    if (tid < 32) {
        float a = b2[tid];
        for (int k = 0; k < 128; k++) a += r1[k] * w2[k * 32 + tid];
        r2[tid] = fmaxf(a, 0.f);
    }
    __syncthreads();
    if (tid == 0) {
        float a = b3[0];
        for (int k = 0; k < 32; k++) a += r2[k] * w3[k];
        out[b] = a;
    }
}

extern "C" void kernel_launch(void* const* d_in, const int* in_sizes, int n_in,
                              void* d_out, int out_size, void* d_ws, size_t ws_size,
                              hipStream_t stream) {
    const float* x  = (const float*)d_in[0];
    const float* dn = (const float*)d_in[1];
    float* out = (float*)d_out;
    float* Hout = out + 16;           // [16384][256] feature/output buffer
    float* ws = (float*)d_ws;
    float* UV   = ws + WS_UV;
    float* rn   = ws + WS_RN;
    int*   nbr  = (int*)(ws + WS_NBR);
    float* WUV  = ws + WS_WUV;
    float* cvec = ws + WS_CVEC;
    float* part = ws + WS_PART;
    float* Xt   = ws + WS_XT;
    unsigned long long* pkeys = (unsigned long long*)UV;   // aliased: dead before k_uv

    hipMemsetAsync(d_out, 0, (size_t)out_size * sizeof(float), stream);

    k_input<<<2048, 128, 0, stream>>>(x, dn,
        (const float*)d_in[2], (const float*)d_in[3],
        (const float*)d_in[4], (const float*)d_in[5],
        (const float*)d_in[6], (const float*)d_in[7], Hout);

    const int convOff[3] = {192, 128, 64};   // input column offset
    const int convD[3]   = {64, 128, 192};   // input feature width
    const int convOut[3] = {128, 64, 0};     // output column offset
    for (int c = 0; c < 3; c++) {
        int pb = 8 + c * 8;
        const float* wa  = (const float*)d_in[pb + 0];
        const float* ba  = (const float*)d_in[pb + 1];
        const float* g   = (const float*)d_in[pb + 2];
        const float* bB  = (const float*)d_in[pb + 3];
        const float* m   = (const float*)d_in[pb + 4];
        const float* v   = (const float*)d_in[pb + 5];
        const float* wb  = (const float*)d_in[pb + 6];
        const float* bbv = (const float*)d_in[pb + 7];
        int D = convD[c], off = convOff[c], co = convOut[c];
        k_prep<<<(D * 192 + 255) / 256, 256, 0, stream>>>(wa, ba, g, bB, m, v, D, WUV, cvec);
        k_tr<<<dim3(D / 64, P / 64, B), 256, 0, stream>>>(Hout, off, D, Xt);
        k_rn2<<<64, 256, 0, stream>>>(Xt, D, rn);
        if (c == 0)      k_knn3<64><<<2048, 256, 0, stream>>>(Xt, rn, pkeys);
        else if (c == 1) k_knn3<128><<<2048, 256, 0, stream>>>(Xt, rn, pkeys);
        else             k_knn3<192><<<2048, 256, 0, stream>>>(Xt, rn, pkeys);
        k_knn_merge<<<1024, 256, 0, stream>>>(pkeys, nbr);
        k_uv<<<1024, 192, 0, stream>>>(Hout, off, D, WUV, UV);
        k_edge<<<4096, 256, 0, stream>>>(UV, nbr, wb, bbv, cvec, co, Hout);
    }

    k_pool<<<256, 256, 0, stream>>>(Hout, part);
    k_out<<<16, 256, 0, stream>>>(part,
        (const float*)d_in[32], (const float*)d_in[33],
        (const float*)d_in[34], (const float*)d_in[35],
        (const float*)d_in[36], (const float*)d_in[37], out);
}